// Round 1
// baseline (255.941 us; speedup 1.0000x reference)
//
#include <hip/hip_runtime.h>

#define HH 512
#define WW 512
#define NIMG 12
#define RAD 3

// Fused-2 tile geometry: output TW x TH, intermediate (TW+6) x (TH+6),
// staged raw region (TW+12) x (TH+12). TW=58 makes the intermediate
// width exactly 64 = one wave -> no ragged column passes in phase 1.
#define TW 58
#define TH 32
#define IW 64            // TW+6, intermediate cols = wave width
#define IH 38            // TH+6, intermediate rows
#define IW2 72           // padded LDS row stride for intermediate
#define SW 70            // TW+12, stage width (lane tx reads cols tx..tx+6, tx<=63 -> 69 ok)
#define SH 46            // TH+12=44 needed + 2 pad rows (ragged last phase-1 pass reads to row 45)
#define GX ((WW + TW - 1) / TW)   // 9 x-tiles (last partial)

typedef float v2 __attribute__((ext_vector_type(2)));

// One side-window-filter iteration over RPW consecutive rows for one wave,
// reading a staged fp32 image+pert pair from LDS and emitting (im',pert')
// per row via the `emit` functor.
//
// NUMERICS CONTRACT (carried from R1-R9 of the previous session):
//  - conv = sequential fma over the 7x7 window, (ky,kx) row-major, one
//    accumulator per direction (bit-exact vs the fp32 ref replay).
//  - IM chains feed argmin -> exact per-chain order preserved:
//      * L/R, NW/NE, SW/SE packed as v_pk_fma lanes; each lane's tap
//        sequence identical to the scalar chain.
//      * U/D are now SCALAR chains (same tap order as before). Rationale:
//        their (row, row+3) operand pairing can't be register-adjacent, so
//        packing cost 28 pk_fma + ~56 v_movs; scalar is 56 fma, strictly
//        cheaper, and scalar fma reads any register half directly.
//  - pi[s][d] holds the pair {row col d, row col d+3}: this is EXACTLY the
//    operand pair of every packed chain -> zero packing movs (the old code
//    rebuilt stride-3 pairs per fma, ~110 movs/px, the hidden VALU cost).
//  - PERT path: quadrant decomposition identical to R5 (absmax 9.77e-4).
template <int RPW, int LDW, class F>
__device__ __forceinline__ void ring_pass(
    const float* __restrict__ SI, const float* __restrict__ SP,
    int r0, int tx, F emit)
{
    const float w28 = 1.0f / 28.0f;   // fp32-rounded, as in the ref kernels
    const float w16 = 0.0625f;        // exact
    const v2 w28v = {w28, w28};
    const v2 w16v = {w16, w16};

    v2    pi[7][4];   // pi[slot][d] = {row[tx+d], row[tx+d+3]}
    v2    hlr[7];     // pert row partials {hl, hr}
    float cc[7];      // pert center column

    auto rowload = [&](int slot, int m) {
        const float* rI = SI + m * LDW + tx;
        float w0 = rI[0], w1 = rI[1], w2 = rI[2], w3 = rI[3],
              w4 = rI[4], w5 = rI[5], w6 = rI[6];
        pi[slot][0] = (v2){w0, w3};
        pi[slot][1] = (v2){w1, w4};
        pi[slot][2] = (v2){w2, w5};
        pi[slot][3] = (v2){w3, w6};
        const float* rP = SP + m * LDW + tx;
        float b0 = rP[0], b1 = rP[1], b2 = rP[2], b3 = rP[3],
              b4 = rP[4], b5 = rP[5], b6 = rP[6];
        hlr[slot] = (v2){(b0 + b1) + (b2 + b3), (b3 + b4) + (b5 + b6)};
        cc[slot] = b3;
    };

    #pragma unroll
    for (int m = 0; m < 7; ++m)
        rowload(m, r0 + m);

    #pragma unroll
    for (int jj = 0; jj < RPW; ++jj) {
        // ---- im: packed L/R, NW/NE, SW/SE + scalar U, D ----
        v2 aLR = {0.f, 0.f}, aQN = {0.f, 0.f}, aQS = {0.f, 0.f};
        #pragma unroll
        for (int dy = 0; dy < 7; ++dy) {
            const int s = (jj + dy) % 7;
            #pragma unroll
            for (int dx = 0; dx < 4; ++dx)   // L: cols 0..3 | R: cols 3..6
                aLR = __builtin_elementwise_fma(pi[s][dx], w28v, aLR);
        }
        float U = 0.f, Dd = 0.f;
        #pragma unroll
        for (int dy = 0; dy < 4; ++dy) {     // U rows 0..3 | D rows 3..6
            const int su = (jj + dy) % 7;
            const int sd = (jj + dy + 3) % 7;
            // cols in order 0..6 = pi[0].x pi[1].x pi[2].x pi[3].x pi[1].y pi[2].y pi[3].y
            U = fmaf(pi[su][0].x, w28, U);  U = fmaf(pi[su][1].x, w28, U);
            U = fmaf(pi[su][2].x, w28, U);  U = fmaf(pi[su][3].x, w28, U);
            U = fmaf(pi[su][1].y, w28, U);  U = fmaf(pi[su][2].y, w28, U);
            U = fmaf(pi[su][3].y, w28, U);
            Dd = fmaf(pi[sd][0].x, w28, Dd); Dd = fmaf(pi[sd][1].x, w28, Dd);
            Dd = fmaf(pi[sd][2].x, w28, Dd); Dd = fmaf(pi[sd][3].x, w28, Dd);
            Dd = fmaf(pi[sd][1].y, w28, Dd); Dd = fmaf(pi[sd][2].y, w28, Dd);
            Dd = fmaf(pi[sd][3].y, w28, Dd);
            #pragma unroll
            for (int dx = 0; dx < 4; ++dx) { // NW/NE top rows, SW/SE bottom
                aQN = __builtin_elementwise_fma(pi[su][dx], w16v, aQN);
                aQS = __builtin_elementwise_fma(pi[sd][dx], w16v, aQS);
            }
        }

        const float cI = pi[(jj + 3) % 7][3].x;   // center col 3
        const v2 cI2 = {cI, cI};
        const v2 d01 = aLR - cI2;
        const float d2 = U - cI, d3 = Dd - cI;
        const v2 d45 = aQN - cI2;
        const v2 d67 = aQS - cI2;
        float d[8] = {d01.x, d01.y, d2, d3, d45.x, d45.y, d67.x, d67.y};

        // ---- pert: packed quadrant decomposition (values identical R5) ----
        float e[8];
        const int p0 = (jj + 0) % 7, p1 = (jj + 1) % 7, p2 = (jj + 2) % 7,
                  p3 = (jj + 3) % 7, p4 = (jj + 4) % 7, p5 = (jj + 5) % 7,
                  p6 = (jj + 6) % 7;
        const float cP = cc[p3];
        {
            v2 qN = ((hlr[p0] + hlr[p1]) + (hlr[p2] + hlr[p3])); // (qnw,qne)
            v2 qS = ((hlr[p3] + hlr[p4]) + (hlr[p5] + hlr[p6])); // (qsw,qse)
            float cu = ((cc[p0] + cc[p1]) + (cc[p2] + cc[p3]));
            float cd = ((cc[p3] + cc[p4]) + (cc[p5] + cc[p6]));
            const v2 cP2 = {cP, cP};
            v2 eLR = (qN + qS - hlr[p3]) * (v2){1.0f/28.0f, 1.0f/28.0f} - cP2;
            v2 eQN = qN * w16v - cP2;
            v2 eQS = qS * w16v - cP2;
            e[0] = eLR.x;  e[1] = eLR.y;
            e[2] = (qN.x + qN.y - cu) * w28 - cP;   // U
            e[3] = (qS.x + qS.y - cd) * w28 - cP;   // D
            e[4] = eQN.x;  e[5] = eQN.y;
            e[6] = eQS.x;  e[7] = eQS.y;
        }

        // first-index-wins argmin over |d| (jnp.argmin tie-break)
        float bestAbs = fabsf(d[0]);
        float bd = d[0];
        float be = e[0];
        #pragma unroll
        for (int j = 1; j < 8; ++j) {
            float a = fabsf(d[j]);
            bool take = a < bestAbs;
            bestAbs = take ? a : bestAbs;
            bd = take ? d[j] : bd;
            be = take ? e[j] : be;
        }

        emit(jj, cI + bd, cP + be);

        if (jj < RPW - 1)
            rowload(jj % 7, r0 + jj + 7);
    }
}

// Fused 2 iterations per dispatch. Phase 1 computes the intermediate
// (iteration k) for the (IH x IW) region into LDS -- zeroed outside the
// image, matching the ref's per-iteration zero padding -- phase 2 computes
// iteration k+1 from LDS and stores to global. The intermediate passes
// through fp32 exactly as it previously did through global memory, so both
// iterations are bit-identical to the unfused 6-dispatch version.
//
// PERF MODEL (R10): dispatch ~= VALU + fixed(~20us). Fusing halves the
// number of fixed-cost round trips (6 -> 3) at the price of ~1.27x compute
// redundancy (halo recompute + 58/64 lane masking), while the pi-pair
// layout removes the ~110 packing movs/px the old packed chains paid.
__global__ __launch_bounds__(256) void swf2(
    const float* __restrict__ im_in, const float* __restrict__ pe_in,
    float* __restrict__ im_out, float* __restrict__ pe_out, int storeIm)
{
    __shared__ float sI0[SH][SW];
    __shared__ float sP0[SH][SW];
    __shared__ float sI1[IH][IW2];
    __shared__ float sP1[IH][IW2];

    const int tid = threadIdx.x;
    const int tx = tid & 63;
    const int wv = tid >> 6;                 // wave id 0..3
    const int x0 = blockIdx.x * TW;
    const int y0 = blockIdx.y * TH;
    const size_t ibase = (size_t)blockIdx.z * (size_t)(HH * WW);
    const float* imb = im_in + ibase;
    const float* peb = pe_in + ibase;

    // Stage raw region [y0-6, y0+40) x [x0-6, x0+64), zero outside image.
    for (int i = tid; i < SH * SW; i += 256) {
        int r = i / SW;
        int c = i - r * SW;
        int gy = y0 - 6 + r;
        int gx = x0 - 6 + c;
        bool ok = ((unsigned)gy < (unsigned)HH) && ((unsigned)gx < (unsigned)WW);
        int gi = gy * WW + gx;
        sI0[r][c] = ok ? imb[gi] : 0.0f;
        sP0[r][c] = ok ? peb[gi] : 0.0f;
    }
    __syncthreads();

    // Phase 1: iteration k over intermediate rows 0..37 (cols = 64 lanes).
    // 8 wave-passes x RPW=5 cover rows 0..39; rows 38,39 masked. Kept at
    // RPW=5 (2 rolled passes) so total code stays inside the 32KB L1I.
    #pragma unroll 1
    for (int pass = 0; pass < 2; ++pass) {
        const int base = (wv + pass * 4) * 5;          // 0,5,...,35
        ring_pass<5, SW>(&sI0[0][0], &sP0[0][0], base, tx,
            [&](int jj, float vI, float vP) {
                int ir = base + jj;
                if (ir < IH) {
                    int gy = y0 - 3 + ir;
                    int gx = x0 - 3 + tx;
                    bool ok = ((unsigned)gy < (unsigned)HH) &&
                              ((unsigned)gx < (unsigned)WW);
                    sI1[ir][tx] = ok ? vI : 0.0f;   // zero = next-iter padding
                    sP1[ir][tx] = ok ? vP : 0.0f;
                }
            });
    }
    __syncthreads();

    // Phase 2: iteration k+1 over output rows 0..31, cols tx<TW valid.
    #pragma unroll 1
    for (int pass = 0; pass < 2; ++pass) {
        const int base = (wv + pass * 4) * 4;          // 0,4,...,28
        ring_pass<4, IW2>(&sI1[0][0], &sP1[0][0], base, tx,
            [&](int jj, float vI, float vP) {
                int gx = x0 + tx;
                if (tx < TW && gx < WW) {
                    size_t gi = ibase + (size_t)(y0 + base + jj) * WW + gx;
                    if (storeIm) im_out[gi] = vI;
                    pe_out[gi] = vP;
                }
            });
    }
}

extern "C" void kernel_launch(void* const* d_in, const int* in_sizes, int n_in,
                              void* d_out, int out_size, void* d_ws, size_t ws_size,
                              hipStream_t stream) {
    const float* im0 = (const float*)d_in[0];
    const float* pe0 = (const float*)d_in[1];
    float* out = (float*)d_out;

    const size_t npix = (size_t)NIMG * HH * WW;   // 3,145,728
    float* imA = (float*)d_ws;                    // 12.6 MB
    float* imB = imA + npix;                      // 12.6 MB
    float* peB = imB + npix;                      // 12.6 MB (ws total 37.7 MB, same as R9)
    // pert ping-pongs through d_out: k1 pert->out, k2 reads out writes peB,
    // k3 reads peB writes out. No kernel reads and writes the same buffer.

    dim3 grid(GX, HH / TH, NIMG);                 // 9 x 16 x 12 = 1728 blocks
    dim3 block(256);

    swf2<<<grid, block, 0, stream>>>(im0, pe0, imA, out, 1);  // iters 0-1
    swf2<<<grid, block, 0, stream>>>(imA, out, imB, peB, 1);  // iters 2-3
    swf2<<<grid, block, 0, stream>>>(imB, peB, imA, out, 0);  // iters 4-5
}